// Round 12
// baseline (75.128 us; speedup 1.0000x reference)
//
#include <hip/hip_runtime.h>

typedef __attribute__((ext_vector_type(8))) short short8;
typedef __attribute__((ext_vector_type(4))) float f32x4;

__device__ __forceinline__ unsigned short f2bf(float f) {
    unsigned u = __builtin_bit_cast(unsigned, f);
    unsigned r = (u + 0x7FFFu + ((u >> 16) & 1u)) >> 16;
    return (unsigned short)r;
}
__device__ __forceinline__ float bf2f(unsigned short u) {
    unsigned v = ((unsigned)u) << 16;
    return __builtin_bit_cast(float, v);
}

#define WAITV(N) asm volatile("s_waitcnt vmcnt(" #N ")" ::: "memory")
#define WAITL0() asm volatile("s_waitcnt lgkmcnt(0)" ::: "memory")
#define BAR() do { asm volatile("" ::: "memory"); __builtin_amdgcn_s_barrier(); asm volatile("" ::: "memory"); } while (0)

// ---- LDS tile swizzle: [128][32] bf16 tile (64B rows). 8-way -> <=2-way. ----
__device__ __forceinline__ short8 lds_read_swz(const unsigned short* tile, int row, int colb) {
    int off = row * 64 + colb;
    off ^= ((off >> 7) & 7) << 4;
    return *(const short8*)((const char*)tile + off);
}

// ---- fp32->bf16 one 8-elem chunk ----
__device__ __forceinline__ void cvt_chunk(const float* __restrict__ src,
                                          unsigned short* __restrict__ dst, int t) {
    const float4* s4 = (const float4*)src;
    float4 a = s4[2 * t], b = s4[2 * t + 1];
    union { unsigned short u[8]; int4 v; } r;
    r.u[0] = f2bf(a.x); r.u[1] = f2bf(a.y); r.u[2] = f2bf(a.z); r.u[3] = f2bf(a.w);
    r.u[4] = f2bf(b.x); r.u[5] = f2bf(b.y); r.u[6] = f2bf(b.z); r.u[7] = f2bf(b.w);
    ((int4*)dst)[t] = r.v;
}

__device__ __forceinline__ short8 pack8(float4 a, float4 b) {
    short8 p;
    p[0] = (short)f2bf(a.x); p[1] = (short)f2bf(a.y);
    p[2] = (short)f2bf(a.z); p[3] = (short)f2bf(a.w);
    p[4] = (short)f2bf(b.x); p[5] = (short)f2bf(b.y);
    p[6] = (short)f2bf(b.z); p[7] = (short)f2bf(b.w);
    return p;
}

#define COMPUTE(cur) do {                                                          \
        short8 af[4], bfr[2];                                                      \
        _Pragma("unroll")                                                          \
        for (int fm = 0; fm < 4; ++fm)                                             \
            af[fm] = lds_read_swz(As[(cur)], wr * 64 + fm * 16 + (lane & 15), (lane >> 4) * 16); \
        _Pragma("unroll")                                                          \
        for (int fn = 0; fn < 2; ++fn)                                             \
            bfr[fn] = lds_read_swz(Bs[(cur)], wc * 32 + fn * 16 + (lane & 15), (lane >> 4) * 16); \
        _Pragma("unroll")                                                          \
        for (int fm = 0; fm < 4; ++fm)                                             \
            _Pragma("unroll")                                                      \
            for (int fn = 0; fn < 2; ++fn)                                         \
                acc[fm][fn] = __builtin_amdgcn_mfma_f32_16x16x32_bf16(             \
                    af[fm], bfr[fn], acc[fm][fn], 0, 0, 0);                        \
    } while (0)

// ======== layer-0 GEMM: fp32 reg-staged depth-3, LDS dbuf, 1 barrier/iter ========
__global__ __launch_bounds__(512) void k_gemm0(
    const float* __restrict__ A, const float* __restrict__ W,
    const float* __restrict__ blend, const float* __restrict__ bias,
    unsigned short* __restrict__ Y,
    const float* __restrict__ csrc, unsigned short* __restrict__ cdst)
{
    __shared__ unsigned short As[2][4096];
    __shared__ unsigned short Bs[2][4096];

    const int e  = blockIdx.z;
    const int bm = blockIdx.y * 128;
    const int on = blockIdx.x * 128;
    const int t  = threadIdx.x, lane = t & 63, w = t >> 6;
    const int wr = w >> 2, wc = w & 3;

    const int sr = lane >> 2, sce = (lane & 3) * 8;
    const int ra = w * 16 + sr;
    const float* gA = A + (size_t)(bm + ra) * 480 + sce;
    const float* gB = W + ((size_t)e * 512 + (on + ra)) * 480 + sce;

    int woff = ra * 64 + (lane & 3) * 16;
    woff ^= ((woff >> 7) & 7) << 4;

    float4 La0[3], La1[3], Lb0[3], Lb1[3];
    #pragma unroll
    for (int s = 0; s < 3; ++s) {
        int k0 = s * 32;
        La0[s] = *(const float4*)(gA + k0); La1[s] = *(const float4*)(gA + k0 + 4);
        Lb0[s] = *(const float4*)(gB + k0); Lb1[s] = *(const float4*)(gB + k0 + 4);
    }

    f32x4 acc[4][2] = {};

    #pragma unroll
    for (int kt = 0; kt < 15; ++kt) {
        const int s = kt % 3, buf = kt & 1;
        *(short8*)((char*)As[buf] + woff) = pack8(La0[s], La1[s]);
        *(short8*)((char*)Bs[buf] + woff) = pack8(Lb0[s], Lb1[s]);
        WAITL0();
        BAR();
        if (kt + 3 < 15) {
            int k0 = (kt + 3) * 32;
            La0[s] = *(const float4*)(gA + k0); La1[s] = *(const float4*)(gA + k0 + 4);
            Lb0[s] = *(const float4*)(gB + k0); Lb1[s] = *(const float4*)(gB + k0 + 4);
        }
        COMPUTE(buf);
    }

    const float* blendE = blend + e * 1024;
    const float* biasE  = bias + (size_t)e * 512;
    unsigned short* Ye  = Y + (size_t)e * 1024 * 512;
    #pragma unroll
    for (int fm = 0; fm < 4; ++fm) {
        int i0 = bm + wr * 64 + fm * 16 + (lane >> 4) * 4;
        float4 bl = *(const float4*)&blendE[i0];
        #pragma unroll
        for (int fn = 0; fn < 2; ++fn) {
            int j = on + wc * 32 + fn * 16 + (lane & 15);
            float bs = biasE[j];
            #pragma unroll
            for (int r = 0; r < 4; ++r)
                Ye[(size_t)(i0 + r) * 512 + j] = f2bf((acc[fm][fn][r] + bs) * ((&bl.x)[r]));
        }
    }

    int lb = (blockIdx.z * 8 + blockIdx.y) * 4 + blockIdx.x;
    cvt_chunk(csrc, cdst, lb * 1024 + threadIdx.x);
    cvt_chunk(csrc, cdst, lb * 1024 + 512 + threadIdx.x);
}

// ======== fused layers 1/2: in-stager plane-reduce + ELU + GEMM ========
// Yin: [8][1024][512] bf16 partial planes (previous layer). A-tile is computed
// on the fly: h = ELU(sum_p Yin[p]) for this block's 128-row band, K-tile by K-tile.
// B reg-staged too; uniform depth-2, vmcnt(9) counted; swizzled ds_writes; 1 bar/iter.
__global__ __launch_bounds__(512) void k_gemm_rho(
    const unsigned short* __restrict__ Yin,
    const unsigned short* __restrict__ W,     // [E][N][512] bf16
    const float* __restrict__ blend, const float* __restrict__ bias,
    unsigned short* __restrict__ Yout,        // [8][1024][ldy] bf16 planes
    int N, int ldy,
    const float* __restrict__ csrc, unsigned short* __restrict__ cdst, int nchunk)
{
    __shared__ unsigned short As[2][4096];
    __shared__ unsigned short Bs[2][4096];

    const int e  = blockIdx.z;
    const int bm = blockIdx.y * 128;
    const int on = blockIdx.x * 128;
    const int t  = threadIdx.x, lane = t & 63, w = t >> 6;
    const int wr = w >> 2, wc = w & 3;

    const int sr = lane >> 2, sc8 = (lane & 3) * 8;
    const int ra = w * 16 + sr;
    const unsigned short* gA = Yin + (size_t)(bm + ra) * 512 + sc8;
    int rb = on + ra; if (rb > N - 1) rb = N - 1;
    const unsigned short* gB = W + ((size_t)e * N + rb) * 512 + sc8;

    int woff = ra * 64 + (lane & 3) * 16;
    woff ^= ((woff >> 7) & 7) << 4;

    int4 Ar0[8], Ar1[8], Br0, Br1;             // two named sets (static idx, rule #20)
    #pragma unroll
    for (int p = 0; p < 8; ++p) Ar0[p] = *(const int4*)(gA + (size_t)p * 524288);
    Br0 = *(const int4*)(gB);
    #pragma unroll
    for (int p = 0; p < 8; ++p) Ar1[p] = *(const int4*)(gA + (size_t)p * 524288 + 32);
    Br1 = *(const int4*)(gB + 32);

    f32x4 acc[4][2] = {};

    #pragma unroll
    for (int kt = 0; kt < 16; ++kt) {
        const int s = kt & 1;
        if (kt == 15) { WAITV(0); } else { WAITV(9); }   // set s retired (9 newer in flight)

        // reduce 8 planes -> h, ELU, pack to bf16x8
        float h[8];
        #pragma unroll
        for (int j = 0; j < 8; ++j) h[j] = 0.f;
        #pragma unroll
        for (int p = 0; p < 8; ++p) {
            const unsigned short* u = s ? (const unsigned short*)&Ar1[p]
                                        : (const unsigned short*)&Ar0[p];
            #pragma unroll
            for (int j = 0; j < 8; ++j) h[j] += bf2f(u[j]);
        }
        short8 aw;
        #pragma unroll
        for (int j = 0; j < 8; ++j) {
            float v = (h[j] > 0.f) ? h[j] : (__expf(h[j]) - 1.0f);
            aw[j] = (short)f2bf(v);
        }
        *(short8*)((char*)As[s] + woff) = aw;
        *(short8*)((char*)Bs[s] + woff) = s ? *(const short8*)&Br1 : *(const short8*)&Br0;
        WAITL0();                              // all this wave's LDS ops retired
        BAR();                                 // tile kt published; old reads done

        if (kt + 2 < 16) {                     // refill set s for tile kt+2
            int c = (kt + 2) * 32;
            if (s) {
                #pragma unroll
                for (int p = 0; p < 8; ++p) Ar1[p] = *(const int4*)(gA + (size_t)p * 524288 + c);
                Br1 = *(const int4*)(gB + c);
            } else {
                #pragma unroll
                for (int p = 0; p < 8; ++p) Ar0[p] = *(const int4*)(gA + (size_t)p * 524288 + c);
                Br0 = *(const int4*)(gB + c);
            }
        }
        COMPUTE(s);
    }

    const float* blendE = blend + e * 1024;
    const float* biasE  = bias + (size_t)e * N;
    unsigned short* Ye  = Yout + (size_t)e * 1024 * ldy;
    #pragma unroll
    for (int fm = 0; fm < 4; ++fm) {
        int i0 = bm + wr * 64 + fm * 16 + (lane >> 4) * 4;
        float4 bl = *(const float4*)&blendE[i0];
        #pragma unroll
        for (int fn = 0; fn < 2; ++fn) {
            int j = on + wc * 32 + fn * 16 + (lane & 15);
            if (j < N) {
                float bs = biasE[j];
                #pragma unroll
                for (int r = 0; r < 4; ++r)
                    Ye[(size_t)(i0 + r) * ldy + j] = f2bf((acc[fm][fn][r] + bs) * ((&bl.x)[r]));
            }
        }
    }

    if (cdst) {                                // tail conversion (w2 during layer 1)
        int lb = (blockIdx.z * 8 + blockIdx.y) * gridDim.x + blockIdx.x;
        #pragma unroll
        for (int q = 0; q < 2; ++q) {
            int tl = q * 512 + threadIdx.x;
            if (tl < nchunk) cvt_chunk(csrc, cdst, lb * nchunk + tl);
        }
    }
}

// ---- final: sum 8 planes (ldy=320), fp32 out, N=311 ----
__global__ __launch_bounds__(256) void k_reduce_last(
    const unsigned short* __restrict__ Y, float* __restrict__ out)
{
    int idx = blockIdx.x * 256 + threadIdx.x;
    if (idx >= 1024 * 40) return;
    int b  = idx / 40;
    int o0 = (idx - b * 40) * 8;
    size_t base = (size_t)b * 320 + o0;
    float s[8] = {};
    #pragma unroll
    for (int p = 0; p < 8; ++p) {
        int4 v = *(const int4*)&Y[base + (size_t)p * 1024 * 320];
        const unsigned short* u = (const unsigned short*)&v;
        #pragma unroll
        for (int r = 0; r < 8; ++r) s[r] += bf2f(u[r]);
    }
    #pragma unroll
    for (int r = 0; r < 8; ++r)
        if (o0 + r < 311) out[(size_t)b * 311 + o0 + r] = s[r];
}

extern "C" void kernel_launch(void* const* d_in, const int* in_sizes, int n_in,
                              void* d_out, int out_size, void* d_ws, size_t ws_size,
                              hipStream_t stream) {
    const float* x     = (const float*)d_in[0];
    const float* blend = (const float*)d_in[1];
    const float* w0    = (const float*)d_in[2];
    const float* b0    = (const float*)d_in[3];
    const float* w1    = (const float*)d_in[4];
    const float* b1    = (const float*)d_in[5];
    const float* w2    = (const float*)d_in[6];
    const float* b2    = (const float*)d_in[7];

    char* ws = (char*)d_ws;
    unsigned short* w1b = (unsigned short*)(ws + 0);          // 4,194,304
    unsigned short* w2b = (unsigned short*)(ws + 4194304);    // 2,547,712
    unsigned short* yb  = (unsigned short*)(ws + 6742016);    // 8,388,608  (L0 planes; L2 planes reuse)
    unsigned short* yb2 = (unsigned short*)(ws + 15130624);   // 8,388,608  (L1 planes)
    // total ~23.5 MB

    // L0: fp32-direct GEMM -> yb planes, + tail-convert w1
    k_gemm0<<<dim3(4, 8, 8), 512, 0, stream>>>(x, w0, blend, b0, yb, w1, w1b);

    // L1: fused reduce(yb)+ELU in stager, GEMM -> yb2 planes, + tail-convert w2
    k_gemm_rho<<<dim3(4, 8, 8), 512, 0, stream>>>(yb, w1b, blend, b1, yb2, 512, 512,
                                                  w2, w2b, 622);

    // L2: fused reduce(yb2)+ELU in stager, GEMM -> yb planes (ldy=320)
    k_gemm_rho<<<dim3(3, 8, 8), 512, 0, stream>>>(yb2, w2b, blend, b2, yb, 311, 320,
                                                  nullptr, nullptr, 0);

    // final: sum planes -> fp32 out
    k_reduce_last<<<160, 256, 0, stream>>>(yb, (float*)d_out);
}

// Round 13
// 55.536 us; speedup vs baseline: 1.3528x; 1.3528x over previous
//
#include <hip/hip_runtime.h>

typedef __attribute__((ext_vector_type(8))) short short8;
typedef __attribute__((ext_vector_type(4))) float f32x4;

__device__ __forceinline__ unsigned short f2bf(float f) {
    unsigned u = __builtin_bit_cast(unsigned, f);
    unsigned r = (u + 0x7FFFu + ((u >> 16) & 1u)) >> 16;
    return (unsigned short)r;
}
__device__ __forceinline__ float bf2f(unsigned short u) {
    unsigned v = ((unsigned)u) << 16;
    return __builtin_bit_cast(float, v);
}

__device__ __forceinline__ void gload16(const unsigned short* g, unsigned short* l) {
    __builtin_amdgcn_global_load_lds(
        (const __attribute__((address_space(1))) void*)g,
        (__attribute__((address_space(3))) void*)l,
        16, 0, 0);
}

#define WAITV(N) asm volatile("s_waitcnt vmcnt(" #N ")" ::: "memory")
#define WAITL0() asm volatile("s_waitcnt lgkmcnt(0)" ::: "memory")
#define BAR() do { asm volatile("" ::: "memory"); __builtin_amdgcn_s_barrier(); asm volatile("" ::: "memory"); } while (0)

// ---- swizzle for [128][32] bf16 tile (64B rows): key = (row>>1)&7 ----
__device__ __forceinline__ short8 lds_read_swz32(const unsigned short* tile, int row, int colb) {
    int off = row * 64 + colb;
    off ^= ((off >> 7) & 7) << 4;
    return *(const short8*)((const char*)tile + off);
}
// ---- swizzle for [128][64] bf16 tile (128B rows): key = row&7 ----
__device__ __forceinline__ short8 lds_read_swz64(const unsigned short* tile, int row, int colb) {
    int off = row * 128 + colb;
    off ^= ((off >> 7) & 7) << 4;
    return *(const short8*)((const char*)tile + off);
}

// ---- fp32->bf16 one 8-elem chunk ----
__device__ __forceinline__ void cvt_chunk(const float* __restrict__ src,
                                          unsigned short* __restrict__ dst, int t) {
    const float4* s4 = (const float4*)src;
    float4 a = s4[2 * t], b = s4[2 * t + 1];
    union { unsigned short u[8]; int4 v; } r;
    r.u[0] = f2bf(a.x); r.u[1] = f2bf(a.y); r.u[2] = f2bf(a.z); r.u[3] = f2bf(a.w);
    r.u[4] = f2bf(b.x); r.u[5] = f2bf(b.y); r.u[6] = f2bf(b.z); r.u[7] = f2bf(b.w);
    ((int4*)dst)[t] = r.v;
}

__device__ __forceinline__ short8 pack8(float4 a, float4 b) {
    short8 p;
    p[0] = (short)f2bf(a.x); p[1] = (short)f2bf(a.y);
    p[2] = (short)f2bf(a.z); p[3] = (short)f2bf(a.w);
    p[4] = (short)f2bf(b.x); p[5] = (short)f2bf(b.y);
    p[6] = (short)f2bf(b.z); p[7] = (short)f2bf(b.w);
    return p;
}

// ======== layer-0 GEMM: fp32 reg-staged depth-3, LDS dbuf, 1 barrier/iter ========
// (R11-validated, unchanged)
__global__ __launch_bounds__(512) void k_gemm0(
    const float* __restrict__ A, const float* __restrict__ W,
    const float* __restrict__ blend, const float* __restrict__ bias,
    unsigned short* __restrict__ Y,
    const float* __restrict__ csrc, unsigned short* __restrict__ cdst)
{
    __shared__ unsigned short As[2][4096];
    __shared__ unsigned short Bs[2][4096];

    const int e  = blockIdx.z;
    const int bm = blockIdx.y * 128;
    const int on = blockIdx.x * 128;
    const int t  = threadIdx.x, lane = t & 63, w = t >> 6;
    const int wr = w >> 2, wc = w & 3;

    const int sr = lane >> 2, sce = (lane & 3) * 8;
    const int ra = w * 16 + sr;
    const float* gA = A + (size_t)(bm + ra) * 480 + sce;
    const float* gB = W + ((size_t)e * 512 + (on + ra)) * 480 + sce;

    int woff = ra * 64 + (lane & 3) * 16;
    woff ^= ((woff >> 7) & 7) << 4;

    float4 La0[3], La1[3], Lb0[3], Lb1[3];
    #pragma unroll
    for (int s = 0; s < 3; ++s) {
        int k0 = s * 32;
        La0[s] = *(const float4*)(gA + k0); La1[s] = *(const float4*)(gA + k0 + 4);
        Lb0[s] = *(const float4*)(gB + k0); Lb1[s] = *(const float4*)(gB + k0 + 4);
    }

    f32x4 acc[4][2] = {};

    #pragma unroll
    for (int kt = 0; kt < 15; ++kt) {
        const int s = kt % 3, buf = kt & 1;
        *(short8*)((char*)As[buf] + woff) = pack8(La0[s], La1[s]);
        *(short8*)((char*)Bs[buf] + woff) = pack8(Lb0[s], Lb1[s]);
        WAITL0();
        BAR();
        if (kt + 3 < 15) {
            int k0 = (kt + 3) * 32;
            La0[s] = *(const float4*)(gA + k0); La1[s] = *(const float4*)(gA + k0 + 4);
            Lb0[s] = *(const float4*)(gB + k0); Lb1[s] = *(const float4*)(gB + k0 + 4);
        }
        short8 af[4], bfr[2];
        #pragma unroll
        for (int fm = 0; fm < 4; ++fm)
            af[fm] = lds_read_swz32(As[buf], wr * 64 + fm * 16 + (lane & 15), (lane >> 4) * 16);
        #pragma unroll
        for (int fn = 0; fn < 2; ++fn)
            bfr[fn] = lds_read_swz32(Bs[buf], wc * 32 + fn * 16 + (lane & 15), (lane >> 4) * 16);
        #pragma unroll
        for (int fm = 0; fm < 4; ++fm)
            #pragma unroll
            for (int fn = 0; fn < 2; ++fn)
                acc[fm][fn] = __builtin_amdgcn_mfma_f32_16x16x32_bf16(
                    af[fm], bfr[fn], acc[fm][fn], 0, 0, 0);
    }

    const float* blendE = blend + e * 1024;
    const float* biasE  = bias + (size_t)e * 512;
    unsigned short* Ye  = Y + (size_t)e * 1024 * 512;
    #pragma unroll
    for (int fm = 0; fm < 4; ++fm) {
        int i0 = bm + wr * 64 + fm * 16 + (lane >> 4) * 4;
        float4 bl = *(const float4*)&blendE[i0];
        #pragma unroll
        for (int fn = 0; fn < 2; ++fn) {
            int j = on + wc * 32 + fn * 16 + (lane & 15);
            float bs = biasE[j];
            #pragma unroll
            for (int r = 0; r < 4; ++r)
                Ye[(size_t)(i0 + r) * 512 + j] = f2bf((acc[fm][fn][r] + bs) * ((&bl.x)[r]));
        }
    }

    int lb = (blockIdx.z * 8 + blockIdx.y) * 4 + blockIdx.x;
    cvt_chunk(csrc, cdst, lb * 1024 + threadIdx.x);
    cvt_chunk(csrc, cdst, lb * 1024 + 512 + threadIdx.x);
}

// ======== layers 1/2: bf16, K=512, BK=64 (8 iters), depth-2, 1 barrier/iter ========
__global__ __launch_bounds__(512) void k_gemm(
    const unsigned short* __restrict__ A,
    const unsigned short* __restrict__ W,
    const float* __restrict__ blend, const float* __restrict__ bias,
    unsigned short* __restrict__ Y,
    int N, int ldy,
    const float* __restrict__ csrc, unsigned short* __restrict__ cdst, int nchunk)
{
    __shared__ unsigned short As[2][8192];   // [128][64] bf16 swizzled, 32 KB
    __shared__ unsigned short Bs[2][8192];   // 32 KB  (total 64 KB)

    const int e  = blockIdx.z;
    const int bm = blockIdx.y * 128;
    const int on = blockIdx.x * 128;
    const int t  = threadIdx.x, lane = t & 63, w = t >> 6;
    const int wr = w >> 2, wc = w & 3;

    const unsigned short* Wt = W + (size_t)e * N * 512;
    // staging: thread covers logical row srow (and srow+64), pre-swizzled source col
    // (rule #21: linear gload dest + inverse-permuted global source)
    const int srow = w * 8 + (lane >> 3);
    const int scol = 8 * ((lane & 7) ^ ((lane >> 3) & 7));
    const unsigned short* gA0 = A + (size_t)(bm + srow) * 512 + scol;
    const unsigned short* gA1 = A + (size_t)(bm + 64 + srow) * 512 + scol;
    int rb0 = on + srow;      if (rb0 > N - 1) rb0 = N - 1;
    int rb1 = on + 64 + srow; if (rb1 > N - 1) rb1 = N - 1;
    const unsigned short* gB0 = Wt + (size_t)rb0 * 512 + scol;
    const unsigned short* gB1 = Wt + (size_t)rb1 * 512 + scol;

#define STAGE(buf, kt) do { int _k = (kt) * 64;                        \
        gload16(gA0 + _k, &As[(buf)][t * 8]);                          \
        gload16(gA1 + _k, &As[(buf)][4096 + t * 8]);                   \
        gload16(gB0 + _k, &Bs[(buf)][t * 8]);                          \
        gload16(gB1 + _k, &Bs[(buf)][4096 + t * 8]); } while (0)

    f32x4 acc[4][2] = {};
    STAGE(0, 0);

    #pragma unroll
    for (int kt = 0; kt < 8; ++kt) {
        const int cur = kt & 1;
        WAITV(0);                        // tile kt's 4 loads retired (issued ~1 iter ago)
        BAR();                           // tile kt readable by all; tile kt-1 reads done
        if (kt + 1 < 8) STAGE(cur ^ 1, kt + 1);
        #pragma unroll
        for (int ks = 0; ks < 2; ++ks) {
            short8 af[4], bfr[2];
            #pragma unroll
            for (int fm = 0; fm < 4; ++fm)
                af[fm] = lds_read_swz64(As[cur], wr * 64 + fm * 16 + (lane & 15),
                                        ks * 64 + (lane >> 4) * 16);
            #pragma unroll
            for (int fn = 0; fn < 2; ++fn)
                bfr[fn] = lds_read_swz64(Bs[cur], wc * 32 + fn * 16 + (lane & 15),
                                         ks * 64 + (lane >> 4) * 16);
            #pragma unroll
            for (int fm = 0; fm < 4; ++fm)
                #pragma unroll
                for (int fn = 0; fn < 2; ++fn)
                    acc[fm][fn] = __builtin_amdgcn_mfma_f32_16x16x32_bf16(
                        af[fm], bfr[fn], acc[fm][fn], 0, 0, 0);
        }
    }
#undef STAGE

    const float* blendE = blend + e * 1024;
    const float* biasE  = bias + (size_t)e * N;
    unsigned short* Ye  = Y + (size_t)e * 1024 * ldy;
    #pragma unroll
    for (int fm = 0; fm < 4; ++fm) {
        int i0 = bm + wr * 64 + fm * 16 + (lane >> 4) * 4;
        float4 bl = *(const float4*)&blendE[i0];
        #pragma unroll
        for (int fn = 0; fn < 2; ++fn) {
            int j = on + wc * 32 + fn * 16 + (lane & 15);
            if (j < N) {
                float bs = biasE[j];
                #pragma unroll
                for (int r = 0; r < 4; ++r)
                    Ye[(size_t)(i0 + r) * ldy + j] = f2bf((acc[fm][fn][r] + bs) * ((&bl.x)[r]));
            }
        }
    }

    if (cdst) {
        int lb = (blockIdx.z * 8 + blockIdx.y) * gridDim.x + blockIdx.x;
        #pragma unroll
        for (int q = 0; q < 2; ++q) {
            int tl = q * 512 + threadIdx.x;
            if (tl < nchunk) cvt_chunk(csrc, cdst, lb * nchunk + tl);
        }
    }
}

// ---- sum 8 bf16 planes + ELU -> bf16 (N=512), 8 elems/thread ----
__global__ __launch_bounds__(256) void k_reduce8(
    const unsigned short* __restrict__ Y, unsigned short* __restrict__ out)
{
    int idx = blockIdx.x * 256 + threadIdx.x;
    int b  = idx >> 6;
    int o0 = (idx & 63) * 8;
    size_t base = (size_t)b * 512 + o0;
    float s[8] = {};
    #pragma unroll
    for (int p = 0; p < 8; ++p) {
        int4 v = *(const int4*)&Y[base + (size_t)p * 1024 * 512];
        const unsigned short* u = (const unsigned short*)&v;
        #pragma unroll
        for (int r = 0; r < 8; ++r) s[r] += bf2f(u[r]);
    }
    union { unsigned short u[8]; int4 v; } rr;
    #pragma unroll
    for (int r = 0; r < 8; ++r) {
        float v = (s[r] > 0.f) ? s[r] : expm1f(s[r]);
        rr.u[r] = f2bf(v);
    }
    *(int4*)&out[base] = rr.v;
}

// ---- final: sum 8 planes (ldy=320), fp32 out, N=311 ----
__global__ __launch_bounds__(256) void k_reduce_last(
    const unsigned short* __restrict__ Y, float* __restrict__ out)
{
    int idx = blockIdx.x * 256 + threadIdx.x;
    if (idx >= 1024 * 40) return;
    int b  = idx / 40;
    int o0 = (idx - b * 40) * 8;
    size_t base = (size_t)b * 320 + o0;
    float s[8] = {};
    #pragma unroll
    for (int p = 0; p < 8; ++p) {
        int4 v = *(const int4*)&Y[base + (size_t)p * 1024 * 320];
        const unsigned short* u = (const unsigned short*)&v;
        #pragma unroll
        for (int r = 0; r < 8; ++r) s[r] += bf2f(u[r]);
    }
    #pragma unroll
    for (int r = 0; r < 8; ++r)
        if (o0 + r < 311) out[(size_t)b * 311 + o0 + r] = s[r];
}

extern "C" void kernel_launch(void* const* d_in, const int* in_sizes, int n_in,
                              void* d_out, int out_size, void* d_ws, size_t ws_size,
                              hipStream_t stream) {
    const float* x     = (const float*)d_in[0];
    const float* blend = (const float*)d_in[1];
    const float* w0    = (const float*)d_in[2];
    const float* b0    = (const float*)d_in[3];
    const float* w1    = (const float*)d_in[4];
    const float* b1    = (const float*)d_in[5];
    const float* w2    = (const float*)d_in[6];
    const float* b2    = (const float*)d_in[7];

    char* ws = (char*)d_ws;
    unsigned short* w1b = (unsigned short*)(ws + 0);         // 4,194,304
    unsigned short* w2b = (unsigned short*)(ws + 4194304);   // 2,547,712
    unsigned short* h1b = (unsigned short*)(ws + 6742016);   // 1,048,576
    unsigned short* h2b = (unsigned short*)(ws + 7790592);   // 1,048,576
    unsigned short* yb  = (unsigned short*)(ws + 8839168);   // 8,388,608 (8 bf16 planes)

    // layer 0: fp32-direct GEMM + tail-convert w1
    k_gemm0<<<dim3(4, 8, 8), 512, 0, stream>>>(x, w0, blend, b0, yb, w1, w1b);
    k_reduce8<<<256, 256, 0, stream>>>(yb, h1b);

    // layer 1: bf16 GEMM (BK=64) + tail-convert w2
    k_gemm<<<dim3(4, 8, 8), 512, 0, stream>>>(h1b, w1b, blend, b1, yb, 512, 512,
                                              w2, w2b, 622);
    k_reduce8<<<256, 256, 0, stream>>>(yb, h2b);

    // layer 2: bf16 GEMM (BK=64), N=311 (ldy=320)
    k_gemm<<<dim3(3, 8, 8), 512, 0, stream>>>(h2b, w2b, blend, b2, yb, 311, 320,
                                              nullptr, nullptr, 0);
    k_reduce_last<<<160, 256, 0, stream>>>(yb, (float*)d_out);
}

// Round 14
// 53.135 us; speedup vs baseline: 1.4139x; 1.0452x over previous
//
#include <hip/hip_runtime.h>

typedef __attribute__((ext_vector_type(8))) short short8;
typedef __attribute__((ext_vector_type(4))) float f32x4;

__device__ __forceinline__ unsigned short f2bf(float f) {
    unsigned u = __builtin_bit_cast(unsigned, f);
    unsigned r = (u + 0x7FFFu + ((u >> 16) & 1u)) >> 16;
    return (unsigned short)r;
}
__device__ __forceinline__ float bf2f(unsigned short u) {
    unsigned v = ((unsigned)u) << 16;
    return __builtin_bit_cast(float, v);
}

__device__ __forceinline__ void gload16(const unsigned short* g, unsigned short* l) {
    __builtin_amdgcn_global_load_lds(
        (const __attribute__((address_space(1))) void*)g,
        (__attribute__((address_space(3))) void*)l,
        16, 0, 0);
}

#define WAITV(N) asm volatile("s_waitcnt vmcnt(" #N ")" ::: "memory")
#define WAITL0() asm volatile("s_waitcnt lgkmcnt(0)" ::: "memory")
#define BAR() do { asm volatile("" ::: "memory"); __builtin_amdgcn_s_barrier(); asm volatile("" ::: "memory"); } while (0)

// ---- LDS tile swizzle: [128][32] bf16 tile (64B rows). 8-way -> <=2-way. ----
__device__ __forceinline__ short8 lds_read_swz(const unsigned short* tile, int row, int colb) {
    int off = row * 64 + colb;
    off ^= ((off >> 7) & 7) << 4;
    return *(const short8*)((const char*)tile + off);
}

// ---- XCD-aware 1D grid decode (T1): 8 y-blocks sharing a W panel (same x,z)
// get ids with identical id%8 -> same XCD -> W panel fetched once per XCD.
__device__ __forceinline__ void xcd_decode(int bid, int nxt, int& x, int& y, int& z) {
    int r = bid & 7, q = bid >> 3;
    y = q & 7;
    int p = (q >> 3) * 8 + r;      // p = x + nxt*z, p in [0, 8*nxt)
    x = p % nxt; z = p / nxt;
}

// ---- fp32->bf16 one 8-elem chunk ----
__device__ __forceinline__ void cvt_chunk(const float* __restrict__ src,
                                          unsigned short* __restrict__ dst, int t) {
    const float4* s4 = (const float4*)src;
    float4 a = s4[2 * t], b = s4[2 * t + 1];
    union { unsigned short u[8]; int4 v; } r;
    r.u[0] = f2bf(a.x); r.u[1] = f2bf(a.y); r.u[2] = f2bf(a.z); r.u[3] = f2bf(a.w);
    r.u[4] = f2bf(b.x); r.u[5] = f2bf(b.y); r.u[6] = f2bf(b.z); r.u[7] = f2bf(b.w);
    ((int4*)dst)[t] = r.v;
}

__device__ __forceinline__ short8 pack8(float4 a, float4 b) {
    short8 p;
    p[0] = (short)f2bf(a.x); p[1] = (short)f2bf(a.y);
    p[2] = (short)f2bf(a.z); p[3] = (short)f2bf(a.w);
    p[4] = (short)f2bf(b.x); p[5] = (short)f2bf(b.y);
    p[6] = (short)f2bf(b.z); p[7] = (short)f2bf(b.w);
    return p;
}

// ======== layer-0 GEMM: fp32 reg-staged depth-3, LDS dbuf, 1 barrier/iter ========
__global__ __launch_bounds__(512) void k_gemm0(
    const float* __restrict__ A, const float* __restrict__ W,
    const float* __restrict__ blend, const float* __restrict__ bias,
    unsigned short* __restrict__ Y,
    const float* __restrict__ csrc, unsigned short* __restrict__ cdst)
{
    __shared__ unsigned short As[2][4096];
    __shared__ unsigned short Bs[2][4096];

    int bx, by, e;
    xcd_decode(blockIdx.x, 4, bx, by, e);
    const int bm = by * 128;
    const int on = bx * 128;
    const int t  = threadIdx.x, lane = t & 63, w = t >> 6;
    const int wr = w >> 2, wc = w & 3;

    const int sr = lane >> 2, sce = (lane & 3) * 8;
    const int ra = w * 16 + sr;
    const float* gA = A + (size_t)(bm + ra) * 480 + sce;
    const float* gB = W + ((size_t)e * 512 + (on + ra)) * 480 + sce;

    int woff = ra * 64 + (lane & 3) * 16;
    woff ^= ((woff >> 7) & 7) << 4;

    float4 La0[3], La1[3], Lb0[3], Lb1[3];
    #pragma unroll
    for (int s = 0; s < 3; ++s) {
        int k0 = s * 32;
        La0[s] = *(const float4*)(gA + k0); La1[s] = *(const float4*)(gA + k0 + 4);
        Lb0[s] = *(const float4*)(gB + k0); Lb1[s] = *(const float4*)(gB + k0 + 4);
    }

    f32x4 acc[4][2] = {};

    #pragma unroll
    for (int kt = 0; kt < 15; ++kt) {
        const int s = kt % 3, buf = kt & 1;
        *(short8*)((char*)As[buf] + woff) = pack8(La0[s], La1[s]);
        *(short8*)((char*)Bs[buf] + woff) = pack8(Lb0[s], Lb1[s]);
        WAITL0();
        BAR();
        if (kt + 3 < 15) {
            int k0 = (kt + 3) * 32;
            La0[s] = *(const float4*)(gA + k0); La1[s] = *(const float4*)(gA + k0 + 4);
            Lb0[s] = *(const float4*)(gB + k0); Lb1[s] = *(const float4*)(gB + k0 + 4);
        }
        short8 af[4], bfr[2];
        #pragma unroll
        for (int fm = 0; fm < 4; ++fm)
            af[fm] = lds_read_swz(As[buf], wr * 64 + fm * 16 + (lane & 15), (lane >> 4) * 16);
        #pragma unroll
        for (int fn = 0; fn < 2; ++fn)
            bfr[fn] = lds_read_swz(Bs[buf], wc * 32 + fn * 16 + (lane & 15), (lane >> 4) * 16);
        #pragma unroll
        for (int fm = 0; fm < 4; ++fm)
            #pragma unroll
            for (int fn = 0; fn < 2; ++fn)
                acc[fm][fn] = __builtin_amdgcn_mfma_f32_16x16x32_bf16(
                    af[fm], bfr[fn], acc[fm][fn], 0, 0, 0);
    }

    const float* blendE = blend + e * 1024;
    const float* biasE  = bias + (size_t)e * 512;
    unsigned short* Ye  = Y + (size_t)e * 1024 * 512;
    #pragma unroll
    for (int fm = 0; fm < 4; ++fm) {
        int i0 = bm + wr * 64 + fm * 16 + (lane >> 4) * 4;
        float4 bl = *(const float4*)&blendE[i0];
        #pragma unroll
        for (int fn = 0; fn < 2; ++fn) {
            int j = on + wc * 32 + fn * 16 + (lane & 15);
            float bs = biasE[j];
            #pragma unroll
            for (int r = 0; r < 4; ++r)
                Ye[(size_t)(i0 + r) * 512 + j] = f2bf((acc[fm][fn][r] + bs) * ((&bl.x)[r]));
        }
    }

    int lb = (e * 8 + by) * 4 + bx;
    cvt_chunk(csrc, cdst, lb * 1024 + threadIdx.x);
    cvt_chunk(csrc, cdst, lb * 1024 + 512 + threadIdx.x);
}

// ======== layers 1/2: bf16, K=512, depth-4 gload16, 1 barrier/iter (R11) ========
__global__ __launch_bounds__(512) void k_gemm(
    const unsigned short* __restrict__ A,
    const unsigned short* __restrict__ W,
    const float* __restrict__ blend, const float* __restrict__ bias,
    unsigned short* __restrict__ Y,
    int N, int ldy, int nxt,
    const float* __restrict__ csrc, unsigned short* __restrict__ cdst, int nchunk)
{
    __shared__ unsigned short As[4][4096];   // 32 KB
    __shared__ unsigned short Bs[4][4096];   // 32 KB

    int bx, by, e;
    xcd_decode(blockIdx.x, nxt, bx, by, e);
    const int bm = by * 128;
    const int on = bx * 128;
    const int t  = threadIdx.x, lane = t & 63, w = t >> 6;
    const int wr = w >> 2, wc = w & 3;

    const unsigned short* Wt = W + (size_t)e * N * 512;
    // pre-swizzled source lane (rule #21): linear gload dest + permuted global src
    const int l2 = lane ^ ((lane >> 3) & 7);
    const int sr = l2 >> 2, sce = (l2 & 3) * 8;
    const int ra = w * 16 + sr;
    int rb = on + ra; if (rb > N - 1) rb = N - 1;
    const unsigned short* gA = A  + (size_t)(bm + ra) * 512 + sce;
    const unsigned short* gB = Wt + (size_t)rb * 512 + sce;

#define STAGE(buf, kt) do { int _k0 = (kt) * 32;                       \
        gload16(gA + _k0, &As[(buf)][w * 512]);                        \
        gload16(gB + _k0, &Bs[(buf)][w * 512]); } while (0)

#define COMPUTE(cur) do {                                                          \
        short8 af[4], bfr[2];                                                      \
        _Pragma("unroll")                                                          \
        for (int fm = 0; fm < 4; ++fm)                                             \
            af[fm] = lds_read_swz(As[(cur)], wr * 64 + fm * 16 + (lane & 15), (lane >> 4) * 16); \
        _Pragma("unroll")                                                          \
        for (int fn = 0; fn < 2; ++fn)                                             \
            bfr[fn] = lds_read_swz(Bs[(cur)], wc * 32 + fn * 16 + (lane & 15), (lane >> 4) * 16); \
        _Pragma("unroll")                                                          \
        for (int fm = 0; fm < 4; ++fm)                                             \
            _Pragma("unroll")                                                      \
            for (int fn = 0; fn < 2; ++fn)                                         \
                acc[fm][fn] = __builtin_amdgcn_mfma_f32_16x16x32_bf16(             \
                    af[fm], bfr[fn], acc[fm][fn], 0, 0, 0);                        \
    } while (0)

    f32x4 acc[4][2] = {};
    STAGE(0, 0); STAGE(1, 1); STAGE(2, 2);   // 6 loads in flight / thread

    for (int kt = 0; kt < 13; ++kt) {
        WAITV(4);
        BAR();                                // tile kt in LDS; tile kt-1 reads done
        STAGE((kt + 3) & 3, kt + 3);          // overwrite tile kt-1's buffer
        COMPUTE(kt & 3);
    }
    WAITV(4); BAR(); COMPUTE(1);
    WAITV(2); BAR(); COMPUTE(2);
    WAITV(0); BAR(); COMPUTE(3);
#undef STAGE

    const float* blendE = blend + e * 1024;
    const float* biasE  = bias + (size_t)e * N;
    unsigned short* Ye  = Y + (size_t)e * 1024 * ldy;
    #pragma unroll
    for (int fm = 0; fm < 4; ++fm) {
        int i0 = bm + wr * 64 + fm * 16 + (lane >> 4) * 4;
        float4 bl = *(const float4*)&blendE[i0];
        #pragma unroll
        for (int fn = 0; fn < 2; ++fn) {
            int j = on + wc * 32 + fn * 16 + (lane & 15);
            if (j < N) {
                float bs = biasE[j];
                #pragma unroll
                for (int r = 0; r < 4; ++r)
                    Ye[(size_t)(i0 + r) * ldy + j] = f2bf((acc[fm][fn][r] + bs) * ((&bl.x)[r]));
            }
        }
    }

    if (cdst) {
        int lb = (e * 8 + by) * nxt + bx;
        #pragma unroll
        for (int q = 0; q < 2; ++q) {
            int tl = q * 512 + threadIdx.x;
            if (tl < nchunk) cvt_chunk(csrc, cdst, lb * nchunk + tl);
        }
    }
}

// ---- sum 8 bf16 planes + ELU -> bf16 (N=512), 8 elems/thread ----
__global__ __launch_bounds__(256) void k_reduce8(
    const unsigned short* __restrict__ Y, unsigned short* __restrict__ out)
{
    int idx = blockIdx.x * 256 + threadIdx.x;
    int b  = idx >> 6;
    int o0 = (idx & 63) * 8;
    size_t base = (size_t)b * 512 + o0;
    float s[8] = {};
    #pragma unroll
    for (int p = 0; p < 8; ++p) {
        int4 v = *(const int4*)&Y[base + (size_t)p * 1024 * 512];
        const unsigned short* u = (const unsigned short*)&v;
        #pragma unroll
        for (int r = 0; r < 8; ++r) s[r] += bf2f(u[r]);
    }
    union { unsigned short u[8]; int4 v; } rr;
    #pragma unroll
    for (int r = 0; r < 8; ++r) {
        float v = (s[r] > 0.f) ? s[r] : expm1f(s[r]);
        rr.u[r] = f2bf(v);
    }
    *(int4*)&out[base] = rr.v;
}

// ---- final: sum 8 planes (ldy=320), fp32 out, N=311 ----
__global__ __launch_bounds__(256) void k_reduce_last(
    const unsigned short* __restrict__ Y, float* __restrict__ out)
{
    int idx = blockIdx.x * 256 + threadIdx.x;
    if (idx >= 1024 * 40) return;
    int b  = idx / 40;
    int o0 = (idx - b * 40) * 8;
    size_t base = (size_t)b * 320 + o0;
    float s[8] = {};
    #pragma unroll
    for (int p = 0; p < 8; ++p) {
        int4 v = *(const int4*)&Y[base + (size_t)p * 1024 * 320];
        const unsigned short* u = (const unsigned short*)&v;
        #pragma unroll
        for (int r = 0; r < 8; ++r) s[r] += bf2f(u[r]);
    }
    #pragma unroll
    for (int r = 0; r < 8; ++r)
        if (o0 + r < 311) out[(size_t)b * 311 + o0 + r] = s[r];
}

extern "C" void kernel_launch(void* const* d_in, const int* in_sizes, int n_in,
                              void* d_out, int out_size, void* d_ws, size_t ws_size,
                              hipStream_t stream) {
    const float* x     = (const float*)d_in[0];
    const float* blend = (const float*)d_in[1];
    const float* w0    = (const float*)d_in[2];
    const float* b0    = (const float*)d_in[3];
    const float* w1    = (const float*)d_in[4];
    const float* b1    = (const float*)d_in[5];
    const float* w2    = (const float*)d_in[6];
    const float* b2    = (const float*)d_in[7];

    char* ws = (char*)d_ws;
    unsigned short* w1b = (unsigned short*)(ws + 0);         // 4,194,304
    unsigned short* w2b = (unsigned short*)(ws + 4194304);   // 2,547,712
    unsigned short* h1b = (unsigned short*)(ws + 6742016);   // 1,048,576
    unsigned short* h2b = (unsigned short*)(ws + 7790592);   // 1,048,576
    unsigned short* yb  = (unsigned short*)(ws + 8839168);   // 8,388,608 (8 bf16 planes)

    // layer 0: fp32-direct GEMM + tail-convert w1 (XCD-swizzled 1D grid)
    k_gemm0<<<256, 512, 0, stream>>>(x, w0, blend, b0, yb, w1, w1b);
    k_reduce8<<<256, 256, 0, stream>>>(yb, h1b);

    // layer 1: bf16 GEMM + tail-convert w2
    k_gemm<<<256, 512, 0, stream>>>(h1b, w1b, blend, b1, yb, 512, 512, 4,
                                    w2, w2b, 622);
    k_reduce8<<<256, 256, 0, stream>>>(yb, h2b);

    // layer 2: bf16 GEMM, N=311 (ldy=320)
    k_gemm<<<192, 512, 0, stream>>>(h2b, w2b, blend, b2, yb, 311, 320, 3,
                                    nullptr, nullptr, 0);
    k_reduce_last<<<160, 256, 0, stream>>>(yb, (float*)d_out);
}